// Round 8
// baseline (476.232 us; speedup 1.0000x reference)
//
#include <hip/hip_runtime.h>

#define D 128
#define SLOTS 64        // max degree per node (Poisson(16))
#define NB 391          // dst bins of 256 nodes: bin = dst >> 8
#define BINCAP 5120     // edges per bin: mean 4092 -> 16 sigma headroom
#define BATCH 2048      // edges per block-batch in k_part
#define EPB 8           // edges per thread per batch
#define CNTSTRIDE 16    // pad global bin counters to 64 B
#define WPITCH 136      // LDS pitch in shorts (272 B rows)

typedef __attribute__((ext_vector_type(8))) short short8;
typedef __attribute__((ext_vector_type(4))) float float4v;

__device__ inline unsigned short f2bf(float f) {
    union { float f; unsigned u; } a; a.f = f;
    unsigned u = a.u;
    return (unsigned short)((u + 0x7fffu + ((u >> 16) & 1u)) >> 16);  // RN-even
}
__device__ inline float bflo(unsigned u) {
    union { unsigned u; float f; } a; a.u = u << 16; return a.f;
}
__device__ inline float bfhi(unsigned u) {
    union { unsigned u; float f; } a; a.u = u & 0xffff0000u; return a.f;
}
__device__ inline unsigned packbf(float a, float b) {
    return (unsigned)f2bf(a) | ((unsigned)f2bf(b) << 16);
}

// ---------- pass 1: counting partition of edges into 391 dst-bins ----------

__global__ __launch_bounds__(256) void k_part(const int* __restrict__ src,
                                              const int* __restrict__ dst, int nE,
                                              int* __restrict__ gcnt, int* __restrict__ bins) {
    __shared__ int hist[512];
    __shared__ int scan[512];
    __shared__ int base[NB];
    __shared__ int stage[BATCH];
    __shared__ int gofs[BATCH];
    int tid = threadIdx.x;
    int start = blockIdx.x * BATCH;
    int cntB = nE - start; if (cntB > BATCH) cntB = BATCH;
    if (cntB <= 0) return;

    hist[tid] = 0; hist[tid + 256] = 0;
    __syncthreads();

    int b[EPB], r[EPB], v[EPB];
    #pragma unroll
    for (int i = 0; i < EPB; ++i) {
        int e = start + i * 256 + tid;
        if (e < nE) {
            int d = dst[e];
            b[i] = d >> 8;
            v[i] = (src[e] << 8) | (d & 255);
            r[i] = atomicAdd(&hist[b[i]], 1);
        } else b[i] = -1;
    }
    __syncthreads();

    scan[tid] = hist[tid]; scan[tid + 256] = hist[tid + 256];
    __syncthreads();
    #pragma unroll
    for (int off = 1; off < 512; off <<= 1) {
        int v0 = (tid >= off) ? scan[tid - off] : 0;
        int v1 = (tid + 256 >= off) ? scan[tid + 256 - off] : 0;
        __syncthreads();
        scan[tid] += v0; scan[tid + 256] += v1;
        __syncthreads();
    }
    if (tid < 256 && tid < NB) base[tid] = atomicAdd(&gcnt[tid * CNTSTRIDE], hist[tid]);
    if (tid + 256 < NB) base[tid + 256] = atomicAdd(&gcnt[(tid + 256) * CNTSTRIDE], hist[tid + 256]);
    __syncthreads();

    #pragma unroll
    for (int i = 0; i < EPB; ++i) {
        if (b[i] >= 0) {
            int p = scan[b[i]] - hist[b[i]] + r[i];
            int o = base[b[i]] + r[i];
            stage[p] = v[i];
            gofs[p] = (o < BINCAP) ? (b[i] * BINCAP + o) : -1;
        }
    }
    __syncthreads();

    #pragma unroll
    for (int i = 0; i < EPB; ++i) {
        int p = i * 256 + tid;
        if (p < cntB) {
            int g = gofs[p];
            if (g >= 0) bins[g] = stage[p];
        }
    }
}

// ---------- pass 2: per-HALF-bin LDS scatter -> dense slot table + degree ----------
// 2 blocks per bin (128 nodes each): 32 KB LDS -> better CU balance (782 blocks).

__global__ __launch_bounds__(256) void k_scatter2(const int* __restrict__ gcnt,
                                                  const int* __restrict__ bins,
                                                  int* __restrict__ slots,
                                                  int* __restrict__ deg, int n, int nAll) {
    __shared__ int slotsL[128 * SLOTS];  // 32 KB
    __shared__ int cntL[128];
    int tid = threadIdx.x;
    int bin = blockIdx.x >> 1;
    int half = blockIdx.x & 1;
    if (tid < 128) cntL[tid] = 0;
    __syncthreads();

    int c = gcnt[bin * CNTSTRIDE]; if (c > BINCAP) c = BINCAP;
    const int* eb = bins + (size_t)bin * BINCAP;
    for (int i = tid; i < c; i += 256) {
        int v = eb[i];
        int dl = v & 255;
        if ((dl >> 7) == half) {
            int p = atomicAdd(&cntL[dl & 127], 1);
            if (p < SLOTS) slotsL[(dl & 127) * SLOTS + p] = v >> 8;
        }
    }
    __syncthreads();

    int node0 = bin * 256 + half * 128;
    int remNodes = n - node0;
    if (remNodes > 128) remNodes = 128;
    if (remNodes < 0) remNodes = 0;

    if (tid < remNodes) {
        int dg = cntL[tid]; if (dg > SLOTS) dg = SLOTS;
        int dgr = (dg + 3) & ~3;
        for (int p = dg; p < dgr; ++p) slotsL[tid * SLOTS + p] = nAll;
        deg[node0 + tid] = dg;
    }
    __syncthreads();

    uint4* gout = reinterpret_cast<uint4*>(slots + (size_t)node0 * SLOTS);
    const uint4* lin = reinterpret_cast<const uint4*>(slotsL);
    int nv = remNodes * SLOTS / 4;
    for (int i = tid; i < nv; i += 256) gout[i] = lin[i];
}

// ---------- fp32 -> bf16 convert (also zeroes the dummy row at index n) ----------

__global__ void k_convert(const float* __restrict__ x, unsigned short* __restrict__ y, int n4) {
    int i = blockIdx.x * 256 + threadIdx.x;
    if (i >= n4 + 32) return;
    uint2 o;
    if (i < n4) {
        float4 v = reinterpret_cast<const float4*>(x)[i];
        o.x = packbf(v.x, v.y);
        o.y = packbf(v.z, v.w);
    } else {
        o.x = 0; o.y = 0;
    }
    reinterpret_cast<uint2*>(y)[i] = o;
}

// ---------- persistent fused aggregate + GEMM, wave-autonomous ----------
// After the one-time Wt staging there is NO inter-wave coupling: each wave
// dynamically claims 16-node chunks (global atomic) and runs
// gather -> in-register A-fragments -> MFMA -> epilogue, barrier-free.
// mode 0: write Y rows (bf16). mode 1: per-lane colsum regs, flushed at end.

__global__ __launch_bounds__(256, 4) void k_fused(const unsigned short* __restrict__ Xin,
                                                  const float* __restrict__ W,
                                                  const float* __restrict__ bias,
                                                  unsigned short* __restrict__ Y,
                                                  float* __restrict__ colsum,
                                                  const int* __restrict__ deg,
                                                  const int* __restrict__ slots,
                                                  int n, int mode,
                                                  int* __restrict__ ctr) {
    __shared__ unsigned short Wt[128 * WPITCH];  // W^T bf16: Wt[ncol][k], 34.8 KB
    __shared__ float cs[128];
    int tid = threadIdx.x;
    int L = tid & 63;
    int m16 = L & 15, g = L >> 4;

    // one-time W -> Wt staging: thread owns (col, k-group-of-8)
    #pragma unroll
    for (int i = 0; i < 8; ++i) {
        int p = i * 256 + tid;           // 0..2047
        int col = p & 127, kg = p >> 7;  // kg 0..15
        unsigned pk[4];
        #pragma unroll
        for (int h = 0; h < 4; ++h) {
            float w0 = W[(kg * 8 + 2 * h + 0) * 128 + col];
            float w1 = W[(kg * 8 + 2 * h + 1) * 128 + col];
            pk[h] = packbf(w0, w1);
        }
        *reinterpret_cast<uint4*>(&Wt[col * WPITCH + kg * 8]) =
            make_uint4(pk[0], pk[1], pk[2], pk[3]);
    }
    if (mode && tid < 128) cs[tid] = 0.f;
    __syncthreads();   // the only barrier before the flush

    float bj[8];
    #pragma unroll
    for (int ct = 0; ct < 8; ++ct) bj[ct] = bias[ct * 16 + m16];
    float csv[8] = {0.f, 0.f, 0.f, 0.f, 0.f, 0.f, 0.f, 0.f};

    int nChunks = (n + 15) >> 4;
    for (;;) {
        int chunk;
        if (L == 0) chunk = atomicAdd(ctr, 1);
        chunk = __shfl(chunk, 0, 64);
        if (chunk >= nChunks) break;

        int node = chunk * 16 + m16;
        float acc[4][8];
        #pragma unroll
        for (int q = 0; q < 4; ++q)
            #pragma unroll
            for (int j = 0; j < 8; ++j) acc[q][j] = 0.f;

        short8 af[4];
        if (node < n) {
            int dg = deg[node];
            int cnt4 = (dg + 3) & ~3;
            const int* sl = slots + (size_t)node * SLOTS;
            const unsigned short* base = Xin + g * 8;
            for (int j = 0; j < cnt4; j += 2) {
                int2 s2 = *reinterpret_cast<const int2*>(sl + j);
                uint4 v0[4], v1[4];
                #pragma unroll
                for (int q = 0; q < 4; ++q)
                    v0[q] = *reinterpret_cast<const uint4*>(base + (size_t)s2.x * D + q * 32);
                #pragma unroll
                for (int q = 0; q < 4; ++q)
                    v1[q] = *reinterpret_cast<const uint4*>(base + (size_t)s2.y * D + q * 32);
                #pragma unroll
                for (int q = 0; q < 4; ++q) {
                    acc[q][0] += bflo(v0[q].x); acc[q][1] += bfhi(v0[q].x);
                    acc[q][2] += bflo(v0[q].y); acc[q][3] += bfhi(v0[q].y);
                    acc[q][4] += bflo(v0[q].z); acc[q][5] += bfhi(v0[q].z);
                    acc[q][6] += bflo(v0[q].w); acc[q][7] += bfhi(v0[q].w);
                    acc[q][0] += bflo(v1[q].x); acc[q][1] += bfhi(v1[q].x);
                    acc[q][2] += bflo(v1[q].y); acc[q][3] += bfhi(v1[q].y);
                    acc[q][4] += bflo(v1[q].z); acc[q][5] += bfhi(v1[q].z);
                    acc[q][6] += bflo(v1[q].w); acc[q][7] += bfhi(v1[q].w);
                }
            }
            float inv = 1.0f / (float)(dg > 0 ? dg : 1);
            #pragma unroll
            for (int q = 0; q < 4; ++q) {
                uint4 sv = *reinterpret_cast<const uint4*>(base + (size_t)node * D + q * 32);
                float o[8];
                o[0] = bflo(sv.x) + acc[q][0] * inv; o[1] = bfhi(sv.x) + acc[q][1] * inv;
                o[2] = bflo(sv.y) + acc[q][2] * inv; o[3] = bfhi(sv.y) + acc[q][3] * inv;
                o[4] = bflo(sv.z) + acc[q][4] * inv; o[5] = bfhi(sv.z) + acc[q][5] * inv;
                o[6] = bflo(sv.w) + acc[q][6] * inv; o[7] = bfhi(sv.w) + acc[q][7] * inv;
                unsigned pk0 = packbf(o[0], o[1]), pk1 = packbf(o[2], o[3]);
                unsigned pk2 = packbf(o[4], o[5]), pk3 = packbf(o[6], o[7]);
                uint4 u = make_uint4(pk0, pk1, pk2, pk3);
                af[q] = *reinterpret_cast<short8*>(&u);
            }
        } else {
            #pragma unroll
            for (int q = 0; q < 4; ++q) af[q] = short8{0,0,0,0,0,0,0,0};
        }

        // MFMA: C(16 rows x 128 cols) per wave
        float4v zero4 = {0.f, 0.f, 0.f, 0.f};
        float4v cacc[8];
        #pragma unroll
        for (int ct = 0; ct < 8; ++ct) cacc[ct] = zero4;
        #pragma unroll
        for (int q = 0; q < 4; ++q) {
            #pragma unroll
            for (int ct = 0; ct < 8; ++ct) {
                short8 b = *reinterpret_cast<const short8*>(&Wt[(ct * 16 + m16) * WPITCH + q * 32 + g * 8]);
                cacc[ct] = __builtin_amdgcn_mfma_f32_16x16x32_bf16(af[q], b, cacc[ct], 0, 0, 0);
            }
        }

        int rowbase = chunk * 16;
        if (mode == 0) {
            #pragma unroll
            for (int i = 0; i < 4; ++i) {
                int row = rowbase + g * 4 + i;
                if (row < n) {
                    #pragma unroll
                    for (int ct = 0; ct < 8; ++ct) {
                        float v = fmaxf(cacc[ct][i] + bj[ct], 0.f);
                        Y[(size_t)row * D + ct * 16 + m16] = f2bf(v);
                    }
                }
            }
        } else {
            #pragma unroll
            for (int i = 0; i < 4; ++i) {
                int row = rowbase + g * 4 + i;
                if (row < n) {
                    #pragma unroll
                    for (int ct = 0; ct < 8; ++ct)
                        csv[ct] += fmaxf(cacc[ct][i] + bj[ct], 0.f);
                }
            }
        }
    }

    if (mode) {
        #pragma unroll
        for (int ct = 0; ct < 8; ++ct) atomicAdd(&cs[ct * 16 + m16], csv[ct]);
        __syncthreads();
        if (tid < 128) atomicAdd(&colsum[tid], cs[tid]);
    }
}

// ---------- readout: out = (colsum/N) @ W3 + b3 ----------

__global__ void k_final(const float* __restrict__ colsum, const float* __restrict__ W3,
                        const float* __restrict__ b3, float* __restrict__ out, float invN) {
    int j = threadIdx.x;  // 128 threads
    float acc = b3[j];
    for (int k = 0; k < D; ++k)
        acc += colsum[k] * invN * W3[k * D + j];
    out[j] = acc;
}

// ---------- launch ----------

extern "C" void kernel_launch(void* const* d_in, const int* in_sizes, int n_in,
                              void* d_out, int out_size, void* d_ws, size_t ws_size,
                              hipStream_t stream) {
    const float* nf = (const float*)d_in[0];
    const int*   ei = (const int*)d_in[1];
    const float* W1 = (const float*)d_in[2];
    const float* b1 = (const float*)d_in[3];
    const float* W2 = (const float*)d_in[4];
    const float* b2 = (const float*)d_in[5];
    const float* W3 = (const float*)d_in[6];
    const float* b3 = (const float*)d_in[7];
    float* out = (float*)d_out;

    int n  = in_sizes[0] / D;
    int nE = in_sizes[1] / 2;
    const int* src = ei;
    const int* dst = ei + nE;

    int nBins = (n + 255) / 256;
    int nBatches = (nE + BATCH - 1) / BATCH;

    char* ws = (char*)d_ws;
    size_t off = 0;
    auto alloc = [&](size_t bytes) -> void* {
        off = (off + 255) & ~(size_t)255;
        void* p = ws + off;
        off += bytes;
        return p;
    };
    int* gcnt  = (int*)alloc((size_t)nBins * CNTSTRIDE * 4);
    int* bins  = (int*)alloc((size_t)nBins * BINCAP * 4);
    int* slots = (int*)alloc((size_t)nBins * 256 * SLOTS * 4);
    int* deg   = (int*)alloc((size_t)n * 4);
    unsigned short* bufA = (unsigned short*)alloc((size_t)(n + 1) * D * 2);
    unsigned short* bufB = (unsigned short*)alloc((size_t)(n + 1) * D * 2);
    float* colsum = (float*)alloc(128 * 4);
    int* ctr = (int*)alloc(2 * 4);          // dynamic chunk counters (layer1, layer2)

    hipMemsetAsync(gcnt, 0, (size_t)nBins * CNTSTRIDE * 4, stream);
    hipMemsetAsync(colsum, 0, 128 * 4, stream);
    hipMemsetAsync(bufB + (size_t)n * D, 0, D * 2, stream);  // bufB dummy zero row
    hipMemsetAsync(ctr, 0, 2 * 4, stream);

    int gC = (n * D / 4 + 32 + 255) / 256;
    const int gP = 1024;   // 4 persistent blocks/CU (LDS 35 KB, launch_bounds(256,4))

    k_part<<<nBatches, 256, 0, stream>>>(src, dst, nE, gcnt, bins);
    k_convert<<<gC, 256, 0, stream>>>(nf, bufA, n * D / 4);   // zeroes bufA row n
    k_scatter2<<<nBins * 2, 256, 0, stream>>>(gcnt, bins, slots, deg, n, n);

    // layer 1: agg(bufA) @ W1 -> bufB
    k_fused<<<gP, 256, 0, stream>>>(bufA, W1, b1, bufB, (float*)nullptr, deg, slots, n, 0, ctr + 0);
    // layer 2: agg(bufB) @ W2 -> colsum
    k_fused<<<gP, 256, 0, stream>>>(bufB, W2, b2, (unsigned short*)nullptr, colsum, deg, slots, n, 1, ctr + 1);
    // readout
    k_final<<<1, 128, 0, stream>>>(colsum, W3, b3, out, 1.0f / (float)n);
}

// Round 9
// 342.653 us; speedup vs baseline: 1.3898x; 1.3898x over previous
//
#include <hip/hip_runtime.h>

#define D 128
#define SLOTS 64        // max degree per node (Poisson(16))
#define NB 391          // dst bins of 256 nodes: bin = dst >> 8
#define BINCAP 5120     // edges per bin: mean 4092 -> 16 sigma headroom
#define BATCH 2048      // edges per block-batch in k_part
#define EPB 8           // edges per thread per batch
#define CNTSTRIDE 16    // pad global bin counters to 64 B
#define WPITCH 136      // LDS pitch in shorts (272 B rows)

typedef __attribute__((ext_vector_type(8))) short short8;
typedef __attribute__((ext_vector_type(4))) float float4v;

__device__ inline unsigned short f2bf(float f) {
    union { float f; unsigned u; } a; a.f = f;
    unsigned u = a.u;
    return (unsigned short)((u + 0x7fffu + ((u >> 16) & 1u)) >> 16);  // RN-even
}
__device__ inline float bflo(unsigned u) {
    union { unsigned u; float f; } a; a.u = u << 16; return a.f;
}
__device__ inline float bfhi(unsigned u) {
    union { unsigned u; float f; } a; a.u = u & 0xffff0000u; return a.f;
}
__device__ inline unsigned packbf(float a, float b) {
    return (unsigned)f2bf(a) | ((unsigned)f2bf(b) << 16);
}

// ---------- pass 1: counting partition of edges into 391 dst-bins ----------
// one block per 2048-edge batch; LDS reorder -> bin-sorted full-line writes.

__global__ __launch_bounds__(256) void k_part(const int* __restrict__ src,
                                              const int* __restrict__ dst, int nE,
                                              int* __restrict__ gcnt, int* __restrict__ bins) {
    __shared__ int hist[512];
    __shared__ int scan[512];
    __shared__ int base[NB];
    __shared__ int stage[BATCH];
    __shared__ int gofs[BATCH];
    int tid = threadIdx.x;
    int start = blockIdx.x * BATCH;
    int cntB = nE - start; if (cntB > BATCH) cntB = BATCH;
    if (cntB <= 0) return;

    hist[tid] = 0; hist[tid + 256] = 0;
    __syncthreads();

    int b[EPB], r[EPB], v[EPB];
    #pragma unroll
    for (int i = 0; i < EPB; ++i) {
        int e = start + i * 256 + tid;
        if (e < nE) {
            int d = dst[e];
            b[i] = d >> 8;
            v[i] = (src[e] << 8) | (d & 255);
            r[i] = atomicAdd(&hist[b[i]], 1);
        } else b[i] = -1;
    }
    __syncthreads();

    scan[tid] = hist[tid]; scan[tid + 256] = hist[tid + 256];
    __syncthreads();
    #pragma unroll
    for (int off = 1; off < 512; off <<= 1) {
        int v0 = (tid >= off) ? scan[tid - off] : 0;
        int v1 = (tid + 256 >= off) ? scan[tid + 256 - off] : 0;
        __syncthreads();
        scan[tid] += v0; scan[tid + 256] += v1;
        __syncthreads();
    }
    if (tid < 256 && tid < NB) base[tid] = atomicAdd(&gcnt[tid * CNTSTRIDE], hist[tid]);
    if (tid + 256 < NB) base[tid + 256] = atomicAdd(&gcnt[(tid + 256) * CNTSTRIDE], hist[tid + 256]);
    __syncthreads();

    #pragma unroll
    for (int i = 0; i < EPB; ++i) {
        if (b[i] >= 0) {
            int p = scan[b[i]] - hist[b[i]] + r[i];
            int o = base[b[i]] + r[i];
            stage[p] = v[i];
            gofs[p] = (o < BINCAP) ? (b[i] * BINCAP + o) : -1;
        }
    }
    __syncthreads();

    #pragma unroll
    for (int i = 0; i < EPB; ++i) {
        int p = i * 256 + tid;
        if (p < cntB) {
            int g = gofs[p];
            if (g >= 0) bins[g] = stage[p];
        }
    }
}

// ---------- pass 2: per-HALF-bin LDS scatter -> dense slot table + degree ----------
// slot lists padded to %8 with dummy zero-row index for 8-wide gather unroll.

__global__ __launch_bounds__(256) void k_scatter2(const int* __restrict__ gcnt,
                                                  const int* __restrict__ bins,
                                                  int* __restrict__ slots,
                                                  int* __restrict__ deg, int n, int nAll) {
    __shared__ int slotsL[128 * SLOTS];  // 32 KB
    __shared__ int cntL[128];
    int tid = threadIdx.x;
    int bin = blockIdx.x >> 1;
    int half = blockIdx.x & 1;
    if (tid < 128) cntL[tid] = 0;
    __syncthreads();

    int c = gcnt[bin * CNTSTRIDE]; if (c > BINCAP) c = BINCAP;
    const int* eb = bins + (size_t)bin * BINCAP;
    for (int i = tid; i < c; i += 256) {
        int v = eb[i];
        int dl = v & 255;
        if ((dl >> 7) == half) {
            int p = atomicAdd(&cntL[dl & 127], 1);
            if (p < SLOTS) slotsL[(dl & 127) * SLOTS + p] = v >> 8;
        }
    }
    __syncthreads();

    int node0 = bin * 256 + half * 128;
    int remNodes = n - node0;
    if (remNodes > 128) remNodes = 128;
    if (remNodes < 0) remNodes = 0;

    if (tid < remNodes) {
        int dg = cntL[tid]; if (dg > SLOTS) dg = SLOTS;
        int dgr = (dg + 7) & ~7;                    // pad to %8
        for (int p = dg; p < dgr; ++p) slotsL[tid * SLOTS + p] = nAll;
        deg[node0 + tid] = dg;
    }
    __syncthreads();

    uint4* gout = reinterpret_cast<uint4*>(slots + (size_t)node0 * SLOTS);
    const uint4* lin = reinterpret_cast<const uint4*>(slotsL);
    int nv = remNodes * SLOTS / 4;
    for (int i = tid; i < nv; i += 256) gout[i] = lin[i];
}

// ---------- fp32 -> bf16 convert (also zeroes the dummy row at index n) ----------

__global__ void k_convert(const float* __restrict__ x, unsigned short* __restrict__ y, int n4) {
    int i = blockIdx.x * 256 + threadIdx.x;
    if (i >= n4 + 32) return;
    uint2 o;
    if (i < n4) {
        float4 v = reinterpret_cast<const float4*>(x)[i];
        o.x = packbf(v.x, v.y);
        o.y = packbf(v.z, v.w);
    } else {
        o.x = 0; o.y = 0;
    }
    reinterpret_cast<uint2*>(y)[i] = o;
}

// ---------- pull aggregation, 8-wide unrolled gathers ----------
// out = x + mean_nbr(x); 16 lanes/node, 8 features/lane (8 acc regs);
// slot lists padded to %8 with zero-row index -> 8 independent row gathers in flight.

__global__ void k_agg(const unsigned short* __restrict__ Xin, unsigned short* __restrict__ Xout,
                      const int* __restrict__ deg, const int* __restrict__ slots, int n) {
    int t = blockIdx.x * 256 + threadIdx.x;
    int node = t >> 4;
    int lane = t & 15;
    if (node >= n) return;
    int dg = deg[node];
    int cnt8 = (dg + 7) & ~7;
    float acc[8] = {0.f, 0.f, 0.f, 0.f, 0.f, 0.f, 0.f, 0.f};
    const int* sl = slots + (size_t)node * SLOTS;
    for (int j = 0; j < cnt8; j += 8) {
        int4 sa = *reinterpret_cast<const int4*>(sl + j);
        int4 sb = *reinterpret_cast<const int4*>(sl + j + 4);
        uint4 v0 = reinterpret_cast<const uint4*>(Xin + (size_t)sa.x * D)[lane];
        uint4 v1 = reinterpret_cast<const uint4*>(Xin + (size_t)sa.y * D)[lane];
        uint4 v2 = reinterpret_cast<const uint4*>(Xin + (size_t)sa.z * D)[lane];
        uint4 v3 = reinterpret_cast<const uint4*>(Xin + (size_t)sa.w * D)[lane];
        uint4 v4 = reinterpret_cast<const uint4*>(Xin + (size_t)sb.x * D)[lane];
        uint4 v5 = reinterpret_cast<const uint4*>(Xin + (size_t)sb.y * D)[lane];
        uint4 v6 = reinterpret_cast<const uint4*>(Xin + (size_t)sb.z * D)[lane];
        uint4 v7 = reinterpret_cast<const uint4*>(Xin + (size_t)sb.w * D)[lane];
        acc[0] += bflo(v0.x); acc[1] += bfhi(v0.x); acc[2] += bflo(v0.y); acc[3] += bfhi(v0.y);
        acc[4] += bflo(v0.z); acc[5] += bfhi(v0.z); acc[6] += bflo(v0.w); acc[7] += bfhi(v0.w);
        acc[0] += bflo(v1.x); acc[1] += bfhi(v1.x); acc[2] += bflo(v1.y); acc[3] += bfhi(v1.y);
        acc[4] += bflo(v1.z); acc[5] += bfhi(v1.z); acc[6] += bflo(v1.w); acc[7] += bfhi(v1.w);
        acc[0] += bflo(v2.x); acc[1] += bfhi(v2.x); acc[2] += bflo(v2.y); acc[3] += bfhi(v2.y);
        acc[4] += bflo(v2.z); acc[5] += bfhi(v2.z); acc[6] += bflo(v2.w); acc[7] += bfhi(v2.w);
        acc[0] += bflo(v3.x); acc[1] += bfhi(v3.x); acc[2] += bflo(v3.y); acc[3] += bfhi(v3.y);
        acc[4] += bflo(v3.z); acc[5] += bfhi(v3.z); acc[6] += bflo(v3.w); acc[7] += bfhi(v3.w);
        acc[0] += bflo(v4.x); acc[1] += bfhi(v4.x); acc[2] += bflo(v4.y); acc[3] += bfhi(v4.y);
        acc[4] += bflo(v4.z); acc[5] += bfhi(v4.z); acc[6] += bflo(v4.w); acc[7] += bfhi(v4.w);
        acc[0] += bflo(v5.x); acc[1] += bfhi(v5.x); acc[2] += bflo(v5.y); acc[3] += bfhi(v5.y);
        acc[4] += bflo(v5.z); acc[5] += bfhi(v5.z); acc[6] += bflo(v5.w); acc[7] += bfhi(v5.w);
        acc[0] += bflo(v6.x); acc[1] += bfhi(v6.x); acc[2] += bflo(v6.y); acc[3] += bfhi(v6.y);
        acc[4] += bflo(v6.z); acc[5] += bfhi(v6.z); acc[6] += bflo(v6.w); acc[7] += bfhi(v6.w);
        acc[0] += bflo(v7.x); acc[1] += bfhi(v7.x); acc[2] += bflo(v7.y); acc[3] += bfhi(v7.y);
        acc[4] += bflo(v7.z); acc[5] += bfhi(v7.z); acc[6] += bflo(v7.w); acc[7] += bfhi(v7.w);
    }
    float inv = 1.0f / (float)(dg > 0 ? dg : 1);
    uint4 sv = reinterpret_cast<const uint4*>(Xin + (size_t)node * D)[lane];
    float o[8];
    o[0] = bflo(sv.x) + acc[0] * inv; o[1] = bfhi(sv.x) + acc[1] * inv;
    o[2] = bflo(sv.y) + acc[2] * inv; o[3] = bfhi(sv.y) + acc[3] * inv;
    o[4] = bflo(sv.z) + acc[4] * inv; o[5] = bfhi(sv.z) + acc[5] * inv;
    o[6] = bflo(sv.w) + acc[6] * inv; o[7] = bfhi(sv.w) + acc[7] * inv;
    uint4 ov;
    ov.x = packbf(o[0], o[1]); ov.y = packbf(o[2], o[3]);
    ov.z = packbf(o[4], o[5]); ov.w = packbf(o[6], o[7]);
    reinterpret_cast<uint4*>(Xout + (size_t)node * D)[lane] = ov;
}

// ---------- MFMA bf16 GEMM: Y = relu(X @ W + b) ----------
// conflict-free Wt staging; mode 0: write Y (bf16); mode 1: fused column-sum.

__global__ __launch_bounds__(256) void k_gemm(const unsigned short* __restrict__ X,
                                              const float* __restrict__ W,
                                              const float* __restrict__ bias,
                                              unsigned short* __restrict__ Y,
                                              float* __restrict__ colsum,
                                              int n, int mode) {
    __shared__ unsigned short Wt[128 * WPITCH];  // W^T bf16: Wt[ncol][k]
    __shared__ float cs[128];
    int tid = threadIdx.x;
    int wave = tid >> 6, L = tid & 63;
    int m16 = L & 15, g = L >> 4;

    // conflict-free W -> Wt: thread owns (col, k-group-of-8)
    #pragma unroll
    for (int i = 0; i < 8; ++i) {
        int p = i * 256 + tid;           // 0..2047
        int col = p & 127, kg = p >> 7;  // kg 0..15
        unsigned pk[4];
        #pragma unroll
        for (int h = 0; h < 4; ++h) {
            float w0 = W[(kg * 8 + 2 * h + 0) * 128 + col];
            float w1 = W[(kg * 8 + 2 * h + 1) * 128 + col];
            pk[h] = packbf(w0, w1);
        }
        *reinterpret_cast<uint4*>(&Wt[col * WPITCH + kg * 8]) =
            make_uint4(pk[0], pk[1], pk[2], pk[3]);
    }
    if (mode && tid < 128) cs[tid] = 0.f;
    __syncthreads();

    int row0 = blockIdx.x * 128 + wave * 32;
    float4v zero4 = {0.f, 0.f, 0.f, 0.f};
    float4v acc[2][8];
    #pragma unroll
    for (int rt = 0; rt < 2; ++rt)
        #pragma unroll
        for (int ct = 0; ct < 8; ++ct) acc[rt][ct] = zero4;

    #pragma unroll
    for (int q = 0; q < 4; ++q) {
        int k0 = q * 32;
        short8 a[2];
        #pragma unroll
        for (int rt = 0; rt < 2; ++rt) {
            int row = row0 + rt * 16 + m16;
            short8 af = {0, 0, 0, 0, 0, 0, 0, 0};
            if (row < n)
                af = *reinterpret_cast<const short8*>(X + (size_t)row * D + k0 + g * 8);
            a[rt] = af;
        }
        #pragma unroll
        for (int ct = 0; ct < 8; ++ct) {
            short8 b = *reinterpret_cast<const short8*>(&Wt[(ct * 16 + m16) * WPITCH + k0 + g * 8]);
            acc[0][ct] = __builtin_amdgcn_mfma_f32_16x16x32_bf16(a[0], b, acc[0][ct], 0, 0, 0);
            acc[1][ct] = __builtin_amdgcn_mfma_f32_16x16x32_bf16(a[1], b, acc[1][ct], 0, 0, 0);
        }
    }

    float bj[8];
    #pragma unroll
    for (int ct = 0; ct < 8; ++ct) bj[ct] = bias[ct * 16 + m16];

    if (mode == 0) {
        #pragma unroll
        for (int rt = 0; rt < 2; ++rt)
            #pragma unroll
            for (int i = 0; i < 4; ++i) {
                int row = row0 + rt * 16 + g * 4 + i;
                if (row < n) {
                    #pragma unroll
                    for (int ct = 0; ct < 8; ++ct) {
                        float v = fmaxf(acc[rt][ct][i] + bj[ct], 0.f);
                        Y[(size_t)row * D + ct * 16 + m16] = f2bf(v);
                    }
                }
            }
    } else {
        float csv[8] = {0.f, 0.f, 0.f, 0.f, 0.f, 0.f, 0.f, 0.f};
        #pragma unroll
        for (int rt = 0; rt < 2; ++rt)
            #pragma unroll
            for (int i = 0; i < 4; ++i) {
                int row = row0 + rt * 16 + g * 4 + i;
                if (row < n) {
                    #pragma unroll
                    for (int ct = 0; ct < 8; ++ct)
                        csv[ct] += fmaxf(acc[rt][ct][i] + bj[ct], 0.f);
                }
            }
        #pragma unroll
        for (int ct = 0; ct < 8; ++ct) atomicAdd(&cs[ct * 16 + m16], csv[ct]);
        __syncthreads();
        if (tid < 128) atomicAdd(&colsum[tid], cs[tid]);
    }
}

// ---------- readout: out = (colsum/N) @ W3 + b3 ----------

__global__ void k_final(const float* __restrict__ colsum, const float* __restrict__ W3,
                        const float* __restrict__ b3, float* __restrict__ out, float invN) {
    int j = threadIdx.x;  // 128 threads
    float acc = b3[j];
    #pragma unroll 8
    for (int k = 0; k < D; ++k)
        acc += colsum[k] * invN * W3[k * D + j];
    out[j] = acc;
}

// ---------- launch ----------

extern "C" void kernel_launch(void* const* d_in, const int* in_sizes, int n_in,
                              void* d_out, int out_size, void* d_ws, size_t ws_size,
                              hipStream_t stream) {
    const float* nf = (const float*)d_in[0];
    const int*   ei = (const int*)d_in[1];
    const float* W1 = (const float*)d_in[2];
    const float* b1 = (const float*)d_in[3];
    const float* W2 = (const float*)d_in[4];
    const float* b2 = (const float*)d_in[5];
    const float* W3 = (const float*)d_in[6];
    const float* b3 = (const float*)d_in[7];
    float* out = (float*)d_out;

    int n  = in_sizes[0] / D;
    int nE = in_sizes[1] / 2;
    const int* src = ei;
    const int* dst = ei + nE;

    int nBins = (n + 255) / 256;
    int nBatches = (nE + BATCH - 1) / BATCH;

    char* ws = (char*)d_ws;
    size_t off = 0;
    auto alloc = [&](size_t bytes) -> void* {
        off = (off + 255) & ~(size_t)255;
        void* p = ws + off;
        off += bytes;
        return p;
    };
    int* gcnt  = (int*)alloc((size_t)nBins * CNTSTRIDE * 4);
    int* bins  = (int*)alloc((size_t)nBins * BINCAP * 4);
    int* slots = (int*)alloc((size_t)nBins * 256 * SLOTS * 4);
    int* deg   = (int*)alloc((size_t)n * 4);
    unsigned short* bufA = (unsigned short*)alloc((size_t)(n + 1) * D * 2);
    unsigned short* bufB = (unsigned short*)alloc((size_t)(n + 1) * D * 2);
    float* colsum = (float*)alloc(128 * 4);

    hipMemsetAsync(gcnt, 0, (size_t)nBins * CNTSTRIDE * 4, stream);
    hipMemsetAsync(colsum, 0, 128 * 4, stream);
    hipMemsetAsync(bufB + (size_t)n * D, 0, D * 2, stream);  // bufB dummy zero row

    int gC = (n * D / 4 + 32 + 255) / 256;
    int gA = (n * 16 + 255) / 256;
    int gG = (n + 127) / 128;

    k_part<<<nBatches, 256, 0, stream>>>(src, dst, nE, gcnt, bins);
    k_convert<<<gC, 256, 0, stream>>>(nf, bufA, n * D / 4);   // zeroes bufA row n
    k_scatter2<<<nBins * 2, 256, 0, stream>>>(gcnt, bins, slots, deg, n, n);

    // layer 1
    k_agg<<<gA, 256, 0, stream>>>(bufA, bufB, deg, slots, n);
    k_gemm<<<gG, 256, 0, stream>>>(bufB, W1, b1, bufA, (float*)nullptr, n, 0);
    // layer 2
    k_agg<<<gA, 256, 0, stream>>>(bufA, bufB, deg, slots, n);
    k_gemm<<<gG, 256, 0, stream>>>(bufB, W2, b2, (unsigned short*)nullptr, colsum, n, 1);
    // readout
    k_final<<<1, 128, 0, stream>>>(colsum, W3, b3, out, 1.0f / (float)n);
}